// Round 1
// baseline (407.233 us; speedup 1.0000x reference)
//
#include <hip/hip_runtime.h>
#include <hip/hip_bf16.h>

typedef __bf16 bf16x8 __attribute__((ext_vector_type(8)));
typedef float  f32x4  __attribute__((ext_vector_type(4)));

#define NTOK 4096
#define CDIM 512
#define HEADS 8
#define HD 64

// ---------------------------------------------------------------------------
// Kernel 1: G[s][b] = x_s[b]^T x_s[b]   (512x512, K=4096), split-bf16 MFMA.
// Tile 128x128, 4 waves, each wave 64x64 (4x4 frags of 16x16x32 bf16).
// LDS tiles stored column-major [col][k] with 16B-chunk XOR swizzle so both
// staging writes and fragment reads are optimal-width b128 ops.
// ---------------------------------------------------------------------------
__global__ __launch_bounds__(256) void gram_kernel(const float* __restrict__ x1,
                                                   const float* __restrict__ x2,
                                                   float* __restrict__ G) {
    const int sb = blockIdx.y;           // s*8 + b
    const int s  = sb >> 3, b = sb & 7;
    const float* xs = (s == 0 ? x1 : x2) + (size_t)b * NTOK * CDIM;
    const int ti = blockIdx.x >> 2, tj = blockIdx.x & 3;
    const int I0 = ti * 128, J0 = tj * 128;

    __shared__ __bf16 ldsIh[128 * 64];
    __shared__ __bf16 ldsIl[128 * 64];
    __shared__ __bf16 ldsJh[128 * 64];
    __shared__ __bf16 ldsJl[128 * 64];

    const int t  = threadIdx.x;
    const int c  = t & 127;              // column within 128-wide tile
    const int kh = t >> 7;               // which 32-row k-half this thread stages

    const int wave = t >> 6;
    const int lane = t & 63;
    const int wm = wave >> 1, wn = wave & 1;
    const int l15 = lane & 15, lk = lane >> 4;

    f32x4 acc[4][4];
    for (int f = 0; f < 4; ++f)
        for (int g = 0; g < 4; ++g)
            acc[f][g] = (f32x4)(0.0f);

    for (int it = 0; it < NTOK / 64; ++it) {
        const int k0 = it * 64;
        __syncthreads();
        // ---- stage I tile and J tile (f32 -> bf16 hi/lo split) ----
        for (int tile = 0; tile < 2; ++tile) {
            const int C0 = tile ? J0 : I0;
            const float* src = xs + (size_t)(k0 + kh * 32) * CDIM + C0 + c;
            __bf16* dh = tile ? ldsJh : ldsIh;
            __bf16* dl = tile ? ldsJl : ldsIl;
            #pragma unroll
            for (int q = 0; q < 4; ++q) {
                float v[8];
                #pragma unroll
                for (int i = 0; i < 8; ++i) v[i] = src[(size_t)(q * 8 + i) * CDIM];
                bf16x8 hv, lv;
                #pragma unroll
                for (int i = 0; i < 8; ++i) {
                    __bf16 h = (__bf16)v[i];
                    hv[i] = h;
                    lv[i] = (__bf16)(v[i] - (float)h);
                }
                const int chunk = (kh * 4 + q) ^ (c & 7);
                const int off = c * 64 + chunk * 8;
                *(bf16x8*)&dh[off] = hv;
                *(bf16x8*)&dl[off] = lv;
            }
        }
        __syncthreads();
        // ---- MFMA: 2 k-steps of 32 ----
        #pragma unroll
        for (int ks = 0; ks < 2; ++ks) {
            bf16x8 ah[4], al[4], bh[4], bl[4];
            #pragma unroll
            for (int f = 0; f < 4; ++f) {
                const int col = wm * 64 + f * 16 + l15;
                const int off = col * 64 + ((ks * 4 + lk) ^ (col & 7)) * 8;
                ah[f] = *(bf16x8*)&ldsIh[off];
                al[f] = *(bf16x8*)&ldsIl[off];
            }
            #pragma unroll
            for (int g = 0; g < 4; ++g) {
                const int col = wn * 64 + g * 16 + l15;
                const int off = col * 64 + ((ks * 4 + lk) ^ (col & 7)) * 8;
                bh[g] = *(bf16x8*)&ldsJh[off];
                bl[g] = *(bf16x8*)&ldsJl[off];
            }
            #pragma unroll
            for (int f = 0; f < 4; ++f)
                #pragma unroll
                for (int g = 0; g < 4; ++g) {
                    acc[f][g] = __builtin_amdgcn_mfma_f32_16x16x32_bf16(ah[f], bh[g], acc[f][g], 0, 0, 0);
                    acc[f][g] = __builtin_amdgcn_mfma_f32_16x16x32_bf16(al[f], bh[g], acc[f][g], 0, 0, 0);
                    acc[f][g] = __builtin_amdgcn_mfma_f32_16x16x32_bf16(ah[f], bl[g], acc[f][g], 0, 0, 0);
                }
        }
    }

    // ---- write out: C/D layout col=lane&15, row=(lane>>4)*4+reg ----
    float* Gout = G + (size_t)sb * CDIM * CDIM;
    for (int f = 0; f < 4; ++f)
        for (int g = 0; g < 4; ++g) {
            const int row0 = I0 + wm * 64 + f * 16 + lk * 4;
            const int col  = J0 + wn * 64 + g * 16 + l15;
            #pragma unroll
            for (int r = 0; r < 4; ++r)
                Gout[(size_t)(row0 + r) * CDIM + col] = acc[f][g][r];
        }
}

// ---------------------------------------------------------------------------
// Kernel 2: T[s][b] = G[s][b] @ Wv_s   (512x512x512 f32)
// ---------------------------------------------------------------------------
__global__ __launch_bounds__(256) void t_kernel(const float* __restrict__ G,
                                                const float* __restrict__ Wkv1,
                                                const float* __restrict__ Wkv2,
                                                float* __restrict__ T) {
    const int sb = blockIdx.y;
    const int s  = sb >> 3;
    const float* W  = (s == 0 ? Wkv1 : Wkv2);
    const float* Gb = G + (size_t)sb * CDIM * CDIM;
    float* Tb = T + (size_t)sb * CDIM * CDIM;
    const int tI = blockIdx.x >> 3, tJ = blockIdx.x & 7;

    __shared__ float Gt[64][65];
    __shared__ float Wt[64][65];

    const int t = threadIdx.x;
    const int tr = t >> 4, tc = t & 15;
    float acc[4][4] = {};

    for (int kc = 0; kc < CDIM; kc += 64) {
        __syncthreads();
        for (int i = 0; i < 16; ++i) {
            const int idx = t + i * 256;
            const int r = idx >> 6, cc = idx & 63;
            Gt[r][cc] = Gb[(size_t)(tI * 64 + r) * CDIM + kc + cc];
            Wt[r][cc] = W[(size_t)(kc + r) * (2 * CDIM) + CDIM + tJ * 64 + cc];
        }
        __syncthreads();
        for (int k = 0; k < 64; ++k) {
            float a[4], bb[4];
            #pragma unroll
            for (int i = 0; i < 4; ++i) a[i] = Gt[tr * 4 + i][k];
            #pragma unroll
            for (int j = 0; j < 4; ++j) bb[j] = Wt[k][tc * 4 + j];
            #pragma unroll
            for (int i = 0; i < 4; ++i)
                #pragma unroll
                for (int j = 0; j < 4; ++j) acc[i][j] += a[i] * bb[j];
        }
    }
    for (int i = 0; i < 4; ++i)
        for (int j = 0; j < 4; ++j)
            Tb[(size_t)(tI * 64 + tr * 4 + i) * CDIM + tJ * 64 + tc * 4 + j] = acc[i][j];
}

// ---------------------------------------------------------------------------
// Kernel 3: ctx[s][b][h] = scale * Wk_h^T T_h ; softmax over d (axis -2) -> SM
// ---------------------------------------------------------------------------
__global__ __launch_bounds__(256) void ctx_kernel(const float* __restrict__ T,
                                                  const float* __restrict__ Wkv1,
                                                  const float* __restrict__ Wkv2,
                                                  float* __restrict__ SM) {
    const int sb = blockIdx.y;
    const int s  = sb >> 3;
    const int h  = blockIdx.x;
    const float* W  = (s == 0 ? Wkv1 : Wkv2);
    const float* Tb = T + (size_t)sb * CDIM * CDIM;

    __shared__ float Kt[64][65];
    __shared__ float Tt[64][65];
    __shared__ float ctxs[64][65];
    __shared__ float mred[64], sred[64];

    const int t = threadIdx.x;
    const int td = t >> 4, te = t & 15;
    float acc[4][4] = {};

    for (int kc = 0; kc < CDIM; kc += 64) {
        __syncthreads();
        for (int i = 0; i < 16; ++i) {
            const int idx = t + i * 256;
            const int r = idx >> 6, cc = idx & 63;
            Kt[r][cc] = W[(size_t)(kc + r) * (2 * CDIM) + h * HD + cc];
            Tt[r][cc] = Tb[(size_t)(kc + r) * CDIM + h * HD + cc];
        }
        __syncthreads();
        for (int k = 0; k < 64; ++k) {
            float a[4], bb[4];
            #pragma unroll
            for (int i = 0; i < 4; ++i) a[i] = Kt[k][td * 4 + i];
            #pragma unroll
            for (int j = 0; j < 4; ++j) bb[j] = Tt[k][te * 4 + j];
            #pragma unroll
            for (int i = 0; i < 4; ++i)
                #pragma unroll
                for (int j = 0; j < 4; ++j) acc[i][j] += a[i] * bb[j];
        }
    }
    const float scale = 0.125f;   // 64^-0.5
    for (int i = 0; i < 4; ++i)
        for (int j = 0; j < 4; ++j)
            ctxs[td * 4 + i][te * 4 + j] = acc[i][j] * scale;
    __syncthreads();
    if (t < 64) {
        float m = -1e30f;
        for (int d = 0; d < 64; ++d) m = fmaxf(m, ctxs[d][t]);
        float ssum = 0.f;
        for (int d = 0; d < 64; ++d) ssum += expf(ctxs[d][t] - m);
        mred[t] = m;
        sred[t] = 1.0f / ssum;
    }
    __syncthreads();
    float* smout = SM + (size_t)(sb * HEADS + h) * HD * HD;
    for (int i = 0; i < 4; ++i)
        for (int j = 0; j < 4; ++j) {
            const int d = td * 4 + i, e = te * 4 + j;
            smout[d * HD + e] = expf(ctxs[d][e] - mred[e]) * sred[e];
        }
}

// ---------------------------------------------------------------------------
// Kernel 4: out_s[b,n,h*64+e] = sum_d x_s[b,n,h*64+d] * SM[1-s][b][h][d][e]
// ---------------------------------------------------------------------------
__global__ __launch_bounds__(256) void out_kernel(const float* __restrict__ x1,
                                                  const float* __restrict__ x2,
                                                  const float* __restrict__ SM,
                                                  float* __restrict__ out) {
    const int sb = blockIdx.z;
    const int s  = sb >> 3, b = sb & 7;
    const int h  = blockIdx.y;
    const int n0 = blockIdx.x * 128;
    const float* xs = (s == 0 ? x1 : x2) + (size_t)b * NTOK * CDIM;
    const float* sm = SM + (size_t)(((1 - s) * 8 + b) * HEADS + h) * HD * HD;

    __shared__ float xt[128][65];
    __shared__ float smt[HD * HD];

    const int t = threadIdx.x;
    for (int i = 0; i < 16; ++i) smt[t + i * 256] = sm[t + i * 256];
    for (int i = 0; i < 32; ++i) {
        const int idx = t + i * 256;
        const int r = idx >> 6, cc = idx & 63;
        xt[r][cc] = xs[(size_t)(n0 + r) * CDIM + h * HD + cc];
    }
    __syncthreads();

    const int el = t & 15, ng = t >> 4;   // cols el*4..+4, rows ng*8..+8
    float acc[8][4] = {};
    for (int d = 0; d < 64; ++d) {
        const float sv0 = smt[d * HD + el * 4 + 0];
        const float sv1 = smt[d * HD + el * 4 + 1];
        const float sv2 = smt[d * HD + el * 4 + 2];
        const float sv3 = smt[d * HD + el * 4 + 3];
        #pragma unroll
        for (int i = 0; i < 8; ++i) {
            const float xv = xt[ng * 8 + i][d];
            acc[i][0] += xv * sv0;
            acc[i][1] += xv * sv1;
            acc[i][2] += xv * sv2;
            acc[i][3] += xv * sv3;
        }
    }
    float* ob = out + (size_t)s * (8ULL * NTOK * CDIM) + (size_t)b * NTOK * CDIM;
    for (int i = 0; i < 8; ++i) {
        float4 v = make_float4(acc[i][0], acc[i][1], acc[i][2], acc[i][3]);
        *(float4*)&ob[(size_t)(n0 + ng * 8 + i) * CDIM + h * HD + el * 4] = v;
    }
}

// ---------------------------------------------------------------------------
extern "C" void kernel_launch(void* const* d_in, const int* in_sizes, int n_in,
                              void* d_out, int out_size, void* d_ws, size_t ws_size,
                              hipStream_t stream) {
    const float* x1   = (const float*)d_in[0];
    const float* x2   = (const float*)d_in[1];
    const float* Wkv1 = (const float*)d_in[2];
    const float* Wkv2 = (const float*)d_in[3];
    float* out = (float*)d_out;

    const size_t GB = 16777216, TB = 16777216, SMB = 2097152;
    // sm always lives in ws (2 MB). G/T go to ws if it's big enough, else
    // into disjoint head/tail regions of d_out (128 MiB), which the final
    // kernel fully overwrites afterwards.
    char* SMp = (char*)d_ws;
    char* Gp;
    char* Tp;
    if (ws_size >= SMB + GB + TB) {
        Gp = (char*)d_ws + SMB;
        Tp = (char*)d_ws + SMB + GB;
    } else {
        Tp = (char*)d_out;                               // [0, 16MiB)
        Gp = (char*)d_out + (134217728 - 16777216);      // last 16MiB
    }

    hipLaunchKernelGGL(gram_kernel, dim3(16, 16), dim3(256), 0, stream,
                       x1, x2, (float*)Gp);
    hipLaunchKernelGGL(t_kernel, dim3(64, 16), dim3(256), 0, stream,
                       (float*)Gp, Wkv1, Wkv2, (float*)Tp);
    hipLaunchKernelGGL(ctx_kernel, dim3(8, 16), dim3(256), 0, stream,
                       (float*)Tp, Wkv1, Wkv2, (float*)SMp);
    hipLaunchKernelGGL(out_kernel, dim3(32, 8, 16), dim3(256), 0, stream,
                       x1, x2, (float*)SMp, out);
}

// Round 2
// 199.622 us; speedup vs baseline: 2.0400x; 2.0400x over previous
//
#include <hip/hip_runtime.h>
#include <hip/hip_bf16.h>

typedef __bf16   bf16x8 __attribute__((ext_vector_type(8)));
typedef _Float16 f16x8  __attribute__((ext_vector_type(8)));
typedef _Float16 f16x4  __attribute__((ext_vector_type(4)));
typedef float    f32x4  __attribute__((ext_vector_type(4)));

#define NTOK 4096
#define CDIM 512
#define HEADS 8
#define HD 64

__device__ __forceinline__ void gload_lds16(const void* g, void* l) {
    __builtin_amdgcn_global_load_lds((const __attribute__((address_space(1))) void*)g,
                                     (__attribute__((address_space(3))) void*)l, 16, 0, 0);
}

// ---------------------------------------------------------------------------
// P1: x [sb][n][c] f32  ->  xt [sb][c][n] fp16  (transpose + convert, once)
// Per block: 64 n x 256 c. Reads coalesced (lane = c), writes 128B/thread.
// ---------------------------------------------------------------------------
__global__ __launch_bounds__(256) void xpose_kernel(const float* __restrict__ x1,
                                                    const float* __restrict__ x2,
                                                    _Float16* __restrict__ xt) {
    const int sb = blockIdx.z, s = sb >> 3, b = sb & 7;
    const float* xs = (s ? x2 : x1) + (size_t)b * NTOK * CDIM;
    const int n0 = blockIdx.x * 64;
    const int t = threadIdx.x, w = t >> 6, l = t & 63;
    const int c = blockIdx.y * 256 + w * 64 + l;

    const float* src = xs + (size_t)n0 * CDIM + c;
    f16x8 v[8];
    #pragma unroll
    for (int q = 0; q < 64; ++q)
        v[q >> 3][q & 7] = (_Float16)src[(size_t)q * CDIM];

    _Float16* dst = xt + (size_t)sb * CDIM * NTOK + (size_t)c * NTOK + n0;
    #pragma unroll
    for (int q = 0; q < 8; ++q)
        *(f16x8*)&dst[q * 8] = v[q];
}

// ---------------------------------------------------------------------------
// P2: Wv = Wkv[:,512:1024] f32 -> wvt_h/wvt_l bf16 [s][j][k] (transpose+split)
// ---------------------------------------------------------------------------
__global__ __launch_bounds__(256) void wtrans_kernel(const float* __restrict__ Wkv1,
                                                     const float* __restrict__ Wkv2,
                                                     __bf16* __restrict__ wvt_h,
                                                     __bf16* __restrict__ wvt_l) {
    const int s = blockIdx.z;
    const float* W = (s ? Wkv2 : Wkv1);
    const int k0 = blockIdx.x * 64;
    const int t = threadIdx.x, w = t >> 6, l = t & 63;
    const int j = blockIdx.y * 256 + w * 64 + l;

    bf16x8 vh[8], vl[8];
    #pragma unroll
    for (int q = 0; q < 64; ++q) {
        float v = W[(size_t)(k0 + q) * (2 * CDIM) + CDIM + j];
        __bf16 h = (__bf16)v;
        vh[q >> 3][q & 7] = h;
        vl[q >> 3][q & 7] = (__bf16)(v - (float)h);
    }
    __bf16* dh = wvt_h + ((size_t)s * CDIM + j) * CDIM + k0;
    __bf16* dl = wvt_l + ((size_t)s * CDIM + j) * CDIM + k0;
    #pragma unroll
    for (int q = 0; q < 8; ++q) {
        *(bf16x8*)&dh[q * 8] = vh[q];
        *(bf16x8*)&dl[q * 8] = vl[q];
    }
}

// ---------------------------------------------------------------------------
// Gram: Gp[split][sb] = xt(k-half)^T xt(k-half), fp16 MFMA, gl_lds staging.
// 512 blocks (2/CU), tile 128x128, LDS 32 KiB, source-swizzled gl_lds.
// ---------------------------------------------------------------------------
__global__ __launch_bounds__(256) void gram_kernel(const _Float16* __restrict__ xt,
                                                   float* __restrict__ Gp) {
    const int id = blockIdx.x;                  // 512
    const int vid = (id & 7) * 64 + (id >> 3);  // XCD-contiguous
    const int sb = vid >> 5, rest = vid & 31;
    const int split = rest >> 4, tile = rest & 15;
    const int I0 = (tile >> 2) * 128, J0 = (tile & 3) * 128;
    const _Float16* xb = xt + (size_t)sb * CDIM * NTOK;

    __shared__ _Float16 Ih[128 * 64];
    __shared__ _Float16 Jh[128 * 64];

    const int t = threadIdx.x, w = t >> 6, l = t & 63;
    const int wm = w >> 1, wn = w & 1, l15 = l & 15, lk = l >> 4;
    const int colr = w * 8 + (l >> 3), pos = l & 7;

    f32x4 acc[4][4];
    #pragma unroll
    for (int f = 0; f < 4; ++f)
        #pragma unroll
        for (int g = 0; g < 4; ++g) acc[f][g] = (f32x4)(0.0f);

    const int kbase = split * 2048;
    for (int it = 0; it < 32; ++it) {
        const int k0 = kbase + it * 64;
        __syncthreads();
        #pragma unroll
        for (int r = 0; r < 4; ++r) {
            const int col = r * 32 + colr;
            const int swz = ((pos ^ (col & 7)) << 3);
            gload_lds16(xb + (size_t)(I0 + col) * NTOK + k0 + swz, &Ih[r * 2048 + w * 512]);
            gload_lds16(xb + (size_t)(J0 + col) * NTOK + k0 + swz, &Jh[r * 2048 + w * 512]);
        }
        __syncthreads();
        #pragma unroll
        for (int ks = 0; ks < 2; ++ks) {
            f16x8 a[4], bb[4];
            #pragma unroll
            for (int f = 0; f < 4; ++f) {
                const int i = wm * 64 + f * 16 + l15;
                a[f] = *(const f16x8*)&Ih[i * 64 + ((ks * 4 + lk) ^ (i & 7)) * 8];
            }
            #pragma unroll
            for (int g = 0; g < 4; ++g) {
                const int j = wn * 64 + g * 16 + l15;
                bb[g] = *(const f16x8*)&Jh[j * 64 + ((ks * 4 + lk) ^ (j & 7)) * 8];
            }
            #pragma unroll
            for (int f = 0; f < 4; ++f)
                #pragma unroll
                for (int g = 0; g < 4; ++g)
                    acc[f][g] = __builtin_amdgcn_mfma_f32_16x16x32_f16(a[f], bb[g], acc[f][g], 0, 0, 0);
        }
    }

    float* Gout = Gp + ((size_t)split * 16 + sb) * CDIM * CDIM;
    #pragma unroll
    for (int f = 0; f < 4; ++f)
        #pragma unroll
        for (int g = 0; g < 4; ++g) {
            const int row0 = I0 + wm * 64 + f * 16 + lk * 4;
            const int col  = J0 + wn * 64 + g * 16 + l15;
            #pragma unroll
            for (int r = 0; r < 4; ++r)
                Gout[(size_t)(row0 + r) * CDIM + col] = acc[f][g][r];
        }
}

// ---------------------------------------------------------------------------
// T = (Gp0+Gp1) @ Wv, split-bf16 3-term MFMA. A reg-staged, B via gl_lds.
// ---------------------------------------------------------------------------
__global__ __launch_bounds__(256) void t_kernel(const float* __restrict__ Gp,
                                                const __bf16* __restrict__ wvt_h,
                                                const __bf16* __restrict__ wvt_l,
                                                float* __restrict__ T) {
    const int id = blockIdx.x;                  // 256
    const int vid = (id & 7) * 32 + (id >> 3);
    const int sb = vid >> 4, tile = vid & 15;
    const int s = sb >> 3;
    const int I0 = (tile >> 2) * 128, J0 = (tile & 3) * 128;
    const float* G0 = Gp + (size_t)sb * CDIM * CDIM;
    const float* G1 = Gp + ((size_t)16 + sb) * CDIM * CDIM;
    const __bf16* Bh = wvt_h + (size_t)s * CDIM * CDIM;
    const __bf16* Bl = wvt_l + (size_t)s * CDIM * CDIM;

    __shared__ __bf16 Ah[128 * 64], Al[128 * 64];
    __shared__ __bf16 Jh[128 * 64], Jl[128 * 64];

    const int t = threadIdx.x, w = t >> 6, l = t & 63;
    const int wm = w >> 1, wn = w & 1, l15 = l & 15, lk = l >> 4;
    const int colr = w * 8 + (l >> 3), pos = l & 7;

    f32x4 acc[4][4];
    #pragma unroll
    for (int f = 0; f < 4; ++f)
        #pragma unroll
        for (int g = 0; g < 4; ++g) acc[f][g] = (f32x4)(0.0f);

    for (int it = 0; it < 8; ++it) {
        const int k0 = it * 64;
        __syncthreads();
        // A stage: read G rows (coalesced), sum partials, split to bf16 hi/lo
        #pragma unroll
        for (int r = 0; r < 4; ++r) {
            const int i = r * 32 + (t >> 3), ch = t & 7;
            const float* g0 = &G0[(size_t)(I0 + i) * CDIM + k0 + ch * 8];
            const float* g1 = &G1[(size_t)(I0 + i) * CDIM + k0 + ch * 8];
            float4 u0 = *(const float4*)g0, u1 = *(const float4*)(g0 + 4);
            float4 w0 = *(const float4*)g1, w1 = *(const float4*)(g1 + 4);
            float vv[8] = {u0.x + w0.x, u0.y + w0.y, u0.z + w0.z, u0.w + w0.w,
                           u1.x + w1.x, u1.y + w1.y, u1.z + w1.z, u1.w + w1.w};
            bf16x8 hh, ll;
            #pragma unroll
            for (int e = 0; e < 8; ++e) {
                __bf16 h = (__bf16)vv[e];
                hh[e] = h;
                ll[e] = (__bf16)(vv[e] - (float)h);
            }
            const int off = i * 64 + ((ch ^ (i & 7)) << 3);
            *(bf16x8*)&Ah[off] = hh;
            *(bf16x8*)&Al[off] = ll;
        }
        // B stage: gl_lds from pre-transposed Wv
        #pragma unroll
        for (int r = 0; r < 4; ++r) {
            const int col = r * 32 + colr;
            const int swz = ((pos ^ (col & 7)) << 3);
            gload_lds16(Bh + (size_t)(J0 + col) * CDIM + k0 + swz, &Jh[r * 2048 + w * 512]);
            gload_lds16(Bl + (size_t)(J0 + col) * CDIM + k0 + swz, &Jl[r * 2048 + w * 512]);
        }
        __syncthreads();
        #pragma unroll
        for (int ks = 0; ks < 2; ++ks) {
            bf16x8 ah[4], al[4], bh[4], bl[4];
            #pragma unroll
            for (int f = 0; f < 4; ++f) {
                const int i = wm * 64 + f * 16 + l15;
                const int off = i * 64 + ((ks * 4 + lk) ^ (i & 7)) * 8;
                ah[f] = *(const bf16x8*)&Ah[off];
                al[f] = *(const bf16x8*)&Al[off];
            }
            #pragma unroll
            for (int g = 0; g < 4; ++g) {
                const int j = wn * 64 + g * 16 + l15;
                const int off = j * 64 + ((ks * 4 + lk) ^ (j & 7)) * 8;
                bh[g] = *(const bf16x8*)&Jh[off];
                bl[g] = *(const bf16x8*)&Jl[off];
            }
            #pragma unroll
            for (int f = 0; f < 4; ++f)
                #pragma unroll
                for (int g = 0; g < 4; ++g) {
                    acc[f][g] = __builtin_amdgcn_mfma_f32_16x16x32_bf16(ah[f], bh[g], acc[f][g], 0, 0, 0);
                    acc[f][g] = __builtin_amdgcn_mfma_f32_16x16x32_bf16(al[f], bh[g], acc[f][g], 0, 0, 0);
                    acc[f][g] = __builtin_amdgcn_mfma_f32_16x16x32_bf16(ah[f], bl[g], acc[f][g], 0, 0, 0);
                }
        }
    }

    float* Tb = T + (size_t)sb * CDIM * CDIM;
    #pragma unroll
    for (int f = 0; f < 4; ++f)
        #pragma unroll
        for (int g = 0; g < 4; ++g) {
            const int row0 = I0 + wm * 64 + f * 16 + lk * 4;
            const int col  = J0 + wn * 64 + g * 16 + l15;
            #pragma unroll
            for (int r = 0; r < 4; ++r)
                Tb[(size_t)(row0 + r) * CDIM + col] = acc[f][g][r];
        }
}

// ---------------------------------------------------------------------------
// ctx: scale * Wk_h^T T_h, softmax over d  ->  smT fp16 [sb][h][e][d]
// ---------------------------------------------------------------------------
__global__ __launch_bounds__(256) void ctx_kernel(const float* __restrict__ T,
                                                  const float* __restrict__ Wkv1,
                                                  const float* __restrict__ Wkv2,
                                                  _Float16* __restrict__ smT) {
    const int sb = blockIdx.y, s = sb >> 3;
    const int h = blockIdx.x;
    const float* W  = (s == 0 ? Wkv1 : Wkv2);
    const float* Tb = T + (size_t)sb * CDIM * CDIM;

    __shared__ float Kt[64][65];
    __shared__ float Tt[64][65];
    __shared__ float ctxs[64][65];
    __shared__ float mred[64], sred[64];

    const int t = threadIdx.x;
    const int td = t >> 4, te = t & 15;
    float acc[4][4] = {};

    for (int kc = 0; kc < CDIM; kc += 64) {
        __syncthreads();
        for (int i = 0; i < 16; ++i) {
            const int idx = t + i * 256;
            const int r = idx >> 6, cc = idx & 63;
            Kt[r][cc] = W[(size_t)(kc + r) * (2 * CDIM) + h * HD + cc];
            Tt[r][cc] = Tb[(size_t)(kc + r) * CDIM + h * HD + cc];
        }
        __syncthreads();
        for (int k = 0; k < 64; ++k) {
            float a[4], bb[4];
            #pragma unroll
            for (int i = 0; i < 4; ++i) a[i] = Kt[k][td * 4 + i];
            #pragma unroll
            for (int j = 0; j < 4; ++j) bb[j] = Tt[k][te * 4 + j];
            #pragma unroll
            for (int i = 0; i < 4; ++i)
                #pragma unroll
                for (int j = 0; j < 4; ++j) acc[i][j] += a[i] * bb[j];
        }
    }
    const float scale = 0.125f;
    for (int i = 0; i < 4; ++i)
        for (int j = 0; j < 4; ++j)
            ctxs[td * 4 + i][te * 4 + j] = acc[i][j] * scale;
    __syncthreads();
    if (t < 64) {
        float m = -1e30f;
        for (int d = 0; d < 64; ++d) m = fmaxf(m, ctxs[d][t]);
        float ssum = 0.f;
        for (int d = 0; d < 64; ++d) ssum += expf(ctxs[d][t] - m);
        mred[t] = m;
        sred[t] = 1.0f / ssum;
    }
    __syncthreads();
    _Float16* smout = smT + (size_t)(sb * HEADS + h) * HD * HD;   // [e][d]
    for (int i = 0; i < 4; ++i)
        for (int j = 0; j < 4; ++j) {
            const int d = td * 4 + i, e = te * 4 + j;
            smout[e * HD + d] = (_Float16)(expf(ctxs[d][e] - mred[e]) * sred[e]);
        }
}

// ---------------------------------------------------------------------------
// out: out_s[n, h*64+e] = sum_d x_s[n, h*64+d] * sm[1-s][h][d][e], fp16 MFMA
// ---------------------------------------------------------------------------
__global__ __launch_bounds__(256) void out_kernel(const float* __restrict__ x1,
                                                  const float* __restrict__ x2,
                                                  const _Float16* __restrict__ smT,
                                                  float* __restrict__ out) {
    const int id = blockIdx.x;                   // 4096
    const int vid = (id & 7) * 512 + (id >> 3);  // h-groups co-XCD
    const int h = vid & 7, nt = (vid >> 3) & 31, sb = vid >> 8;
    const int s = sb >> 3, b = sb & 7;
    const float* xs = (s ? x2 : x1) + (size_t)b * NTOK * CDIM;
    const _Float16* sm = smT + (size_t)((((1 - s) * 8 + b) * HEADS) + h) * HD * HD;
    const int n0 = nt * 128;

    __shared__ _Float16 Axt[128 * 64];   // [n][d] swizzled
    __shared__ _Float16 Bsm[64 * 64];    // [e][d] swizzled

    const int t = threadIdx.x, w = t >> 6, l = t & 63;
    const int l15 = l & 15, lk = l >> 4;

    // B stage via gl_lds (2 rounds)
    #pragma unroll
    for (int r = 0; r < 2; ++r) {
        const int e = r * 32 + w * 8 + (l >> 3), pos = l & 7;
        gload_lds16(sm + (size_t)e * HD + ((pos ^ (e & 7)) << 3), &Bsm[r * 2048 + w * 512]);
    }
    // A stage: x f32 -> fp16, swizzled ds_write_b64
    #pragma unroll
    for (int p = 0; p < 8; ++p) {
        const int row = p * 16 + (t >> 4), f4c = t & 15;
        float4 u = *(const float4*)&xs[(size_t)(n0 + row) * CDIM + h * HD + f4c * 4];
        f16x4 q = {(_Float16)u.x, (_Float16)u.y, (_Float16)u.z, (_Float16)u.w};
        const int byte = row * 128 + (((f4c >> 1) ^ (row & 7)) << 4) + ((f4c & 1) << 3);
        *(f16x4*)((char*)Axt + byte) = q;
    }
    __syncthreads();

    f32x4 acc[2][4];
    #pragma unroll
    for (int m = 0; m < 2; ++m)
        #pragma unroll
        for (int g = 0; g < 4; ++g) acc[m][g] = (f32x4)(0.0f);

    #pragma unroll
    for (int ks = 0; ks < 2; ++ks) {
        f16x8 a[2], bb[4];
        #pragma unroll
        for (int m = 0; m < 2; ++m) {
            const int row = w * 32 + m * 16 + l15;
            a[m] = *(const f16x8*)((char*)Axt + row * 128 + (((ks * 4 + lk) ^ (row & 7)) << 4));
        }
        #pragma unroll
        for (int g = 0; g < 4; ++g) {
            const int e = g * 16 + l15;
            bb[g] = *(const f16x8*)((char*)Bsm + e * 128 + (((ks * 4 + lk) ^ (e & 7)) << 4));
        }
        #pragma unroll
        for (int m = 0; m < 2; ++m)
            #pragma unroll
            for (int g = 0; g < 4; ++g)
                acc[m][g] = __builtin_amdgcn_mfma_f32_16x16x32_f16(a[m], bb[g], acc[m][g], 0, 0, 0);
    }

    float* ob = out + (size_t)s * (8ULL * NTOK * CDIM) + (size_t)b * NTOK * CDIM;
    #pragma unroll
    for (int m = 0; m < 2; ++m)
        #pragma unroll
        for (int g = 0; g < 4; ++g) {
            const int row0 = n0 + w * 32 + m * 16 + lk * 4;
            const int col  = h * HD + g * 16 + l15;
            #pragma unroll
            for (int r = 0; r < 4; ++r)
                ob[(size_t)(row0 + r) * CDIM + col] = acc[m][g][r];
        }
}

// ---------------------------------------------------------------------------
extern "C" void kernel_launch(void* const* d_in, const int* in_sizes, int n_in,
                              void* d_out, int out_size, void* d_ws, size_t ws_size,
                              hipStream_t stream) {
    const float* x1   = (const float*)d_in[0];
    const float* x2   = (const float*)d_in[1];
    const float* Wkv1 = (const float*)d_in[2];
    const float* Wkv2 = (const float*)d_in[3];
    float* out = (float*)d_out;

    // Scratch layout inside d_out (128 MiB); every region is dead before
    // out_kernel overwrites d_out. smT (1 MiB) lives in d_ws.
    char* base = (char*)d_out;
    _Float16* XT   = (_Float16*)(base + 0);            // 64 MiB
    __bf16*   WVTH = (__bf16*)(base + 67108864);       // 1 MiB
    __bf16*   WVTL = (__bf16*)(base + 68157440);       // 1 MiB
    float*    GP   = (float*)(base + 69206016);        // 32 MiB (2 partials)
    float*    T    = (float*)(base + 102760448);       // 16 MiB (ends at 114 MiB)
    _Float16* SMT  = (_Float16*)d_ws;                  // 1 MiB

    hipLaunchKernelGGL(xpose_kernel, dim3(64, 2, 16), dim3(256), 0, stream, x1, x2, XT);
    hipLaunchKernelGGL(wtrans_kernel, dim3(8, 2, 2), dim3(256), 0, stream, Wkv1, Wkv2, WVTH, WVTL);
    hipLaunchKernelGGL(gram_kernel, dim3(512), dim3(256), 0, stream, XT, GP);
    hipLaunchKernelGGL(t_kernel, dim3(256), dim3(256), 0, stream, GP, WVTH, WVTL, T);
    hipLaunchKernelGGL(ctx_kernel, dim3(8, 16), dim3(256), 0, stream, T, Wkv1, Wkv2, SMT);
    hipLaunchKernelGGL(out_kernel, dim3(4096), dim3(256), 0, stream, x1, x2, SMT, out);
}